// Round 11
// baseline (136.254 us; speedup 1.0000x reference)
//
#include <hip/hip_runtime.h>
#include <cstdint>
#include <cfloat>
#include <cmath>

#define NPTS 65536
#define NB 16
#define NS 20
#define KK 10
#define NSm1 (NS - 1)
#define WPB 64      // waves per batch (16 blocks x 4 waves)

struct InitIdx { int idx[NB]; };

static __device__ __forceinline__ unsigned long long
agent_ld(const unsigned long long* p) {
    return __hip_atomic_load(p, __ATOMIC_RELAXED, __HIP_MEMORY_SCOPE_AGENT);
}

// ---------------- Kernel 1: barrier-free distributed FPS (exact JAX) --------
// COVERAGE: 16 blocks/batch x 256 thr (4 waves) x 16 pts = 65536  ✓✓
// (R9/R10 bug: 1 block x 1024 x 16 = 16384 — only a quarter of the cloud.)
// Each of a batch's 64 waves is an independent sync agent: per step it does a
// packed-u64 wave argmax (fbits(val)<<32 | ~idx -> max val, tie -> smallest
// idx = JAX argmax first-occurrence), lane0 publishes slot [s][W] via relaxed
// agent store; all waves poll the 64 slots (slot l on lane l, one coalesced
// 512B load) and butterfly-reduce. NO __syncthreads anywhere in the loop —
// no block reduce, no LDS, publish at earliest per-wave moment (min jitter).
// 256 blocks <= 256 CUs -> co-residency guaranteed (no deadlock).
__global__ __launch_bounds__(256, 1) void fps_kernel(const float* __restrict__ pcs,
                                                     int* __restrict__ seeds,
                                                     unsigned long long* __restrict__ fkey,
                                                     InitIdx init) {
    const int u   = blockIdx.x;         // 0..255
    const int xcd = u & 7;              // XCD heuristic (perf-only)
    const int k   = u >> 3;             // 0..31
    const int b   = 2 * xcd + (k >> 4); // batch
    const int j   = k & 15;             // block-in-batch
    const int t   = threadIdx.x;        // 0..255
    const int lane = t & 63;
    const int w    = t >> 6;            // 0..3
    const int W    = j * 4 + w;         // wave id within batch, 0..63
    const float* __restrict__ base = pcs + (size_t)b * NPTS * 3;
    const int pbase = W * 1024 + lane * 16;   // 16 contiguous points

    float x[16], y[16], z[16], dm[16];
    {
        const float4* q4 = reinterpret_cast<const float4*>(base + (size_t)pbase * 3);
#pragma unroll
        for (int g = 0; g < 4; ++g) {
            float4 A = q4[g * 3 + 0], Bv = q4[g * 3 + 1], Cv = q4[g * 3 + 2];
            x[g*4+0] = A.x;  y[g*4+0] = A.y;  z[g*4+0] = A.z;
            x[g*4+1] = A.w;  y[g*4+1] = Bv.x; z[g*4+1] = Bv.y;
            x[g*4+2] = Bv.z; y[g*4+2] = Bv.w; z[g*4+2] = Cv.x;
            x[g*4+3] = Cv.y; y[g*4+3] = Cv.z; z[g*4+3] = Cv.w;
        }
#pragma unroll
        for (int q = 0; q < 16; ++q) dm[q] = 1e10f;
    }

    int far = init.idx[b];

    for (int s = 0; s < NS; ++s) {
        if (j == 0 && w == 0 && lane == 0) seeds[b * NS + s] = far;  // pre-update
        if (s == NSm1) break;                      // last update/argmax unused

        const float cx = base[(size_t)far * 3 + 0];   // uniform, cached
        const float cy = base[(size_t)far * 3 + 1];
        const float cz = base[(size_t)far * 3 + 2];

        float bestv = -1.0f;
        int   besti = 0;
#pragma unroll
        for (int q = 0; q < 16; ++q) {
            // match XLA: rounded sub/mul, sequential adds, NO fma contraction
            float dx = __fsub_rn(x[q], cx);
            float dy = __fsub_rn(y[q], cy);
            float dz = __fsub_rn(z[q], cz);
            float d  = __fadd_rn(__fadd_rn(__fmul_rn(dx, dx), __fmul_rn(dy, dy)),
                                 __fmul_rn(dz, dz));
            dm[q] = fminf(dm[q], d);
            // q ascending = index ascending; strict > keeps first occurrence
            if (dm[q] > bestv) { bestv = dm[q]; besti = pbase + q; }
        }

        // packed wave argmax: monotone for val>=0; tie -> larger ~idx = smaller idx
        unsigned long long kv =
            ((unsigned long long)__float_as_uint(bestv) << 32) |
            (unsigned long long)(0xFFFFFFFFu - (unsigned int)besti);
#pragma unroll
        for (int off = 32; off >= 1; off >>= 1) {
            unsigned int lo = (unsigned int)kv, hi = (unsigned int)(kv >> 32);
            unsigned int olo = (unsigned int)__shfl_xor((int)lo, off);
            unsigned int ohi = (unsigned int)__shfl_xor((int)hi, off);
            unsigned long long o = ((unsigned long long)ohi << 32) | olo;
            if (o > kv) kv = o;
        }

        unsigned long long* fp = fkey + (size_t)(b * NS + s) * WPB;
        if (lane == 0)
            __hip_atomic_store(&fp[W], kv, __ATOMIC_RELAXED,
                               __HIP_MEMORY_SCOPE_AGENT);

        // poll all 64 slots (lane l watches slot l), then butterfly max-reduce
        unsigned long long v;
        do { v = agent_ld(&fp[lane]); } while (__any(v == 0ULL));
#pragma unroll
        for (int off = 32; off >= 1; off >>= 1) {
            unsigned int lo = (unsigned int)v, hi = (unsigned int)(v >> 32);
            unsigned int olo = (unsigned int)__shfl_xor((int)lo, off);
            unsigned int ohi = (unsigned int)__shfl_xor((int)hi, off);
            unsigned long long o = ((unsigned long long)ohi << 32) | olo;
            if (o > v) v = o;
        }
        far = (int)(0xFFFFFFFFu - (unsigned int)(v & 0xFFFFFFFFull));
    }
}

// ---------------- Kernel 2: per-seed 11 smallest distances + repulsion ------
// One block (1024 thr) per (batch, seed), XCD-mapped. Branchless sorted
// insert via med3 (exonerated by R9/R10 bisection: identical output to the
// bubble version): new[j] = med3(l[j-1], l[j], sq) descending j, then
// l[0] = min(l[0], sq) — no serial dependency chain, no divergence.
// Wave-level 11-pop merge, single-wave final merge. sqrt monotone.
__global__ __launch_bounds__(1024) void knn_kernel(const float* __restrict__ pcs,
                                                   const int* __restrict__ seeds,
                                                   float* __restrict__ out) {
    const int u   = blockIdx.x;        // 0..319
    const int xcd = u & 7;
    const int k   = u >> 3;            // 0..39
    const int b   = 2 * xcd + (k & 1);
    const int s   = k >> 1;            // 0..19
    const int t = threadIdx.x;
    const int lane = t & 63;
    const int w = t >> 6;              // wave id 0..15
    const float* __restrict__ base = pcs + (size_t)b * NPTS * 3;
    const int sidx = seeds[b * NS + s];
    const float cx = base[(size_t)sidx * 3 + 0];
    const float cy = base[(size_t)sidx * 3 + 1];
    const float cz = base[(size_t)sidx * 3 + 2];

    float lst[11];
#pragma unroll
    for (int jj = 0; jj < 11; ++jj) lst[jj] = FLT_MAX;

    for (int i = 0; i < 16; ++i) {
        const int pbase = i * 4096 + t * 4;
        const float4* q4 = reinterpret_cast<const float4*>(base + (size_t)pbase * 3);
        float4 A = q4[0], Bv = q4[1], Cv = q4[2];
        float px[4] = { A.x, A.w, Bv.z, Cv.y };
        float py[4] = { A.y, Bv.x, Bv.w, Cv.z };
        float pz[4] = { A.z, Bv.y, Cv.x, Cv.w };
#pragma unroll
        for (int q = 0; q < 4; ++q) {
            float dx = __fsub_rn(px[q], cx);
            float dy = __fsub_rn(py[q], cy);
            float dz = __fsub_rn(pz[q], cz);
            float sq = __fadd_rn(__fadd_rn(__fmul_rn(dx, dx), __fmul_rn(dy, dy)),
                                 __fmul_rn(dz, dz));
            // branchless sorted insert, all ops independent (med3 trick)
#pragma unroll
            for (int jj = 10; jj >= 1; --jj)
                lst[jj] = __builtin_amdgcn_fmed3f(lst[jj - 1], lst[jj], sq);
            lst[0] = fminf(lst[0], sq);
        }
    }

    // ---- wave-level top-11: 11 rounds of (wave-min of heads, pop one copy) --
    __shared__ float s_top[16][11];
    for (int r = 0; r < 11; ++r) {
        float v = lst[0];
#pragma unroll
        for (int off = 32; off >= 1; off >>= 1) v = fminf(v, __shfl_xor(v, off));
        unsigned long long m = __ballot(lst[0] == v);
        if (lane == (int)__ffsll(m) - 1) {     // pop exactly one copy
#pragma unroll
            for (int jj = 0; jj < 10; ++jj) lst[jj] = lst[jj + 1];
            lst[10] = FLT_MAX;
        }
        if (lane == 0) s_top[w][r] = v;
    }
    __syncthreads();

    // ---- final merge: wave 0 merges 16 lists x 11 = 176 values -------------
    if (w == 0) {
        const float* flat = &s_top[0][0];
        float a0 = flat[lane];
        float a1 = flat[lane + 64];
        float a2 = (lane + 128 < 176) ? flat[lane + 128] : FLT_MAX;

        const float HH = (float)(0.01 * 0.01);   // JAX weak-typed scalar H*H
        float acc = 0.0f;
#pragma unroll
        for (int r = 0; r < 11; ++r) {
            float mymin = fminf(a0, fminf(a1, a2));
            float v = mymin;
#pragma unroll
            for (int off = 32; off >= 1; off >>= 1) v = fminf(v, __shfl_xor(v, off));
            unsigned long long m = __ballot(mymin == v);
            if (lane == (int)__ffsll(m) - 1) {
                if (a0 == v)      a0 = FLT_MAX;
                else if (a1 == v) a1 = FLT_MAX;
                else              a2 = FLT_MAX;
            }
            if (lane == 0 && r >= 1) {           // r==0 is self (dist 0)
                float sq = v;
                float d  = (sq == 0.0f) ? 0.0f : __fsqrt_rn(sq);
                float q2 = __fmul_rn(d, d);
                float wt = expf(__fdiv_rn(-q2, HH));
                acc = __fadd_rn(acc, -__fmul_rn(d, wt));
            }
        }
        if (lane == 0) atomicAdd(out, acc * 0.0625f);   // mean over B=16
    }
}

// ---------------- Host: JAX threefry2x32 (partitionable mode) ---------------
static inline uint32_t rotl32(uint32_t x, uint32_t d) { return (x << d) | (x >> (32 - d)); }

static void tf2x32(uint32_t k0, uint32_t k1, uint32_t x0, uint32_t x1,
                   uint32_t& y0, uint32_t& y1) {
    const uint32_t ks[3] = { k0, k1, k0 ^ k1 ^ 0x1BD11BDAu };
    const uint32_t rotA[4] = { 13, 15, 26, 6 };
    const uint32_t rotB[4] = { 17, 29, 16, 24 };
    uint32_t v0 = x0 + ks[0], v1 = x1 + ks[1];
    for (int i = 0; i < 5; ++i) {
        const uint32_t* rot = (i % 2 == 0) ? rotA : rotB;
        for (int j = 0; j < 4; ++j) {
            v0 += v1;
            v1 = rotl32(v1, rot[j]);
            v1 ^= v0;
        }
        v0 += ks[(i + 1) % 3];
        v1 += ks[(i + 2) % 3] + (uint32_t)(i + 1);
    }
    y0 = v0; y1 = v1;
}

extern "C" void kernel_launch(void* const* d_in, const int* in_sizes, int n_in,
                              void* d_out, int out_size, void* d_ws, size_t ws_size,
                              hipStream_t stream) {
    const float* pcs = (const float*)d_in[0];
    float* out = (float*)d_out;

    // ws: [0,1280) seeds (int); [2048, 2048+16*20*64*8=165888) fps keys (u64)
    int* seeds               = (int*)d_ws;
    unsigned long long* fkey = (unsigned long long*)((char*)d_ws + 2048);

    // jax.random.key(1) -> threefry key (0,1), partitionable mode:
    //   split foldlike: k2 = threefry((0,1),(0,1)) both words
    //   random_bits: counters (0,i), out = y0 ^ y1; randint span 2^16 -> mask
    uint32_t k2_0, k2_1;
    tf2x32(0u, 1u, 0u, 1u, k2_0, k2_1);
    InitIdx init;
    for (int i = 0; i < NB; ++i) {
        uint32_t y0, y1;
        tf2x32(k2_0, k2_1, 0u, (uint32_t)i, y0, y1);
        init.idx[i] = (int)((y0 ^ y1) & 0xFFFFu);
    }

    hipMemsetAsync(d_ws, 0, 165888, stream);   // seeds + fps key slots
    hipMemsetAsync(d_out, 0, sizeof(float), stream);

    hipLaunchKernelGGL(fps_kernel, dim3(256), dim3(256), 0, stream,
                       pcs, seeds, fkey, init);
    hipLaunchKernelGGL(knn_kernel, dim3(NB * NS), dim3(1024), 0, stream,
                       pcs, seeds, out);
}

// Round 12
// 82.349 us; speedup vs baseline: 1.6546x; 1.6546x over previous
//
#include <hip/hip_runtime.h>
#include <cstdint>
#include <cfloat>
#include <cmath>

#define NPTS 65536
#define NB 16
#define NS 20
#define KK 10
#define FPB 16      // FPS blocks per batch
#define NSm1 (NS - 1)

struct InitIdx { int idx[NB]; };

static __device__ __forceinline__ unsigned long long
agent_ld(const unsigned long long* p) {
    return __hip_atomic_load(p, __ATOMIC_RELAXED, __HIP_MEMORY_SCOPE_AGENT);
}

// ---------------- Kernel 1: distributed FPS (R8-verbatim, 45 us) ------------
// 256 blocks (16/batch) x 1024 threads; 4 CONTIGUOUS points/thread loaded once
// as 3x float4, coords + running-min in registers the whole kernel.
// Per step: compute d, dm=min(dm,d), wave argmax (strict >, tie -> smaller
// index = JAX first-occurrence), B1, wave0: parallel 16-lane block reduce ->
// lane0 publishes packed u64 key (fbits(val)<<32 | ~idx, monotone, nonzero)
// via relaxed agent store; wave0 polls the batch's 16 keys with a 3-deep
// pipelined load loop, shuffle-max-reduces, B2.
__global__ __launch_bounds__(1024) void fps_kernel(const float* __restrict__ pcs,
                                                   int* __restrict__ seeds,
                                                   unsigned long long* __restrict__ fkey,
                                                   InitIdx init) {
    const int u   = blockIdx.x;
    const int xcd = u & 7;              // XCD heuristic (perf-only)
    const int k   = u >> 3;             // 0..31
    const int b   = 2 * xcd + (k >> 4); // batch
    const int j   = k & 15;             // block-in-batch
    const int t   = threadIdx.x;
    const int lane = t & 63;
    const int w    = t >> 6;
    const float* __restrict__ base = pcs + (size_t)b * NPTS * 3;
    const int pbase = j * 4096 + t * 4; // 4 contiguous points per thread

    const float4* q4 = reinterpret_cast<const float4*>(base + (size_t)pbase * 3);
    float4 A = q4[0], Bv = q4[1], Cv = q4[2];
    float x[4] = { A.x, A.w, Bv.z, Cv.y };
    float y[4] = { A.y, Bv.x, Bv.w, Cv.z };
    float z[4] = { A.z, Bv.y, Cv.x, Cv.w };
    float dm[4] = { 1e10f, 1e10f, 1e10f, 1e10f };

    __shared__ float s_val[16];
    __shared__ int   s_idx[16];
    __shared__ int   s_far;

    int far = init.idx[b];

    for (int s = 0; s < NS; ++s) {
        if (j == 0 && t == 0) seeds[b * NS + s] = far;   // seed s BEFORE update
        if (s == NSm1) break;                            // last update unused

        const float* c = base + (size_t)far * 3;         // uniform, cached
        const float cx = c[0], cy = c[1], cz = c[2];

        float bestv = -1.0f;
        int   besti = 0;
#pragma unroll
        for (int q = 0; q < 4; ++q) {
            // match XLA: rounded sub/mul, sequential adds, NO fma contraction
            float dx = __fsub_rn(x[q], cx);
            float dy = __fsub_rn(y[q], cy);
            float dz = __fsub_rn(z[q], cz);
            float d  = __fadd_rn(__fadd_rn(__fmul_rn(dx, dx), __fmul_rn(dy, dy)),
                                 __fmul_rn(dz, dz));
            dm[q] = fminf(dm[q], d);
            // q ascending = index ascending; strict > keeps first occurrence
            if (dm[q] > bestv) { bestv = dm[q]; besti = pbase + q; }
        }
#pragma unroll
        for (int off = 32; off >= 1; off >>= 1) {
            float ov = __shfl_down(bestv, off);
            int   oi = __shfl_down(besti, off);
            if (ov > bestv || (ov == bestv && oi < besti)) { bestv = ov; besti = oi; }
        }
        if (lane == 0) { s_val[w] = bestv; s_idx[w] = besti; }
        __syncthreads();                                 // B1

        if (w == 0) {
            // parallel 16-lane block reduce -> packed key -> publish
            unsigned long long kv = 0ULL;
            if (lane < 16) {
                kv = ((unsigned long long)__float_as_uint(s_val[lane]) << 32) |
                     (unsigned long long)(0xFFFFFFFFu - (unsigned int)s_idx[lane]);
            }
#pragma unroll
            for (int off = 8; off >= 1; off >>= 1) {
                unsigned int lo = (unsigned int)kv, hi = (unsigned int)(kv >> 32);
                unsigned int olo = (unsigned int)__shfl_xor((int)lo, off);
                unsigned int ohi = (unsigned int)__shfl_xor((int)hi, off);
                unsigned long long o = ((unsigned long long)ohi << 32) | olo;
                if (o > kv) kv = o;
            }
            unsigned long long* fp = fkey + (size_t)(b * NS + s) * FPB;
            if (lane == 0)
                __hip_atomic_store(&fp[j], kv, __ATOMIC_RELAXED,
                                   __HIP_MEMORY_SCOPE_AGENT);

            // 3-deep pipelined poll of the 16 slots (lane l watches slot l&15)
            const unsigned long long* sl = fp + (lane & 15);
            unsigned long long p0 = agent_ld(sl);
            unsigned long long p1 = agent_ld(sl);
            unsigned long long p2 = agent_ld(sl);
            unsigned long long v;
            for (;;) {
                if (!__any(p0 == 0ULL)) { v = p0; break; }
                p0 = agent_ld(sl);
                if (!__any(p1 == 0ULL)) { v = p1; break; }
                p1 = agent_ld(sl);
                if (!__any(p2 == 0ULL)) { v = p2; break; }
                p2 = agent_ld(sl);
            }
#pragma unroll
            for (int off = 32; off >= 1; off >>= 1) {
                unsigned int lo = (unsigned int)v, hi = (unsigned int)(v >> 32);
                unsigned int olo = (unsigned int)__shfl_xor((int)lo, off);
                unsigned int ohi = (unsigned int)__shfl_xor((int)hi, off);
                unsigned long long o = ((unsigned long long)ohi << 32) | olo;
                if (o > v) v = o;
            }
            if (lane == 0)
                s_far = (int)(0xFFFFFFFFu - (unsigned int)(v & 0xFFFFFFFFull));
        }
        __syncthreads();                                 // B2
        far = s_far;
    }
}

// ---------------- Kernel 2: per-seed knn + repulsion (R11-verbatim) ---------
// One block (1024 thr) per (batch, seed), XCD-mapped. Branchless sorted
// insert via med3 (exonerated by R9/R10 bisection): new[j] = med3(l[j-1],
// l[j], sq) descending j, then l[0] = min(l[0], sq) — no serial chain, no
// divergence. Wave-level 11-pop merge, single-wave final merge.
__global__ __launch_bounds__(1024) void knn_kernel(const float* __restrict__ pcs,
                                                   const int* __restrict__ seeds,
                                                   float* __restrict__ out) {
    const int u   = blockIdx.x;        // 0..319
    const int xcd = u & 7;
    const int k   = u >> 3;            // 0..39
    const int b   = 2 * xcd + (k & 1);
    const int s   = k >> 1;            // 0..19
    const int t = threadIdx.x;
    const int lane = t & 63;
    const int w = t >> 6;              // wave id 0..15
    const float* __restrict__ base = pcs + (size_t)b * NPTS * 3;
    const int sidx = seeds[b * NS + s];
    const float cx = base[(size_t)sidx * 3 + 0];
    const float cy = base[(size_t)sidx * 3 + 1];
    const float cz = base[(size_t)sidx * 3 + 2];

    float lst[11];
#pragma unroll
    for (int jj = 0; jj < 11; ++jj) lst[jj] = FLT_MAX;

    for (int i = 0; i < 16; ++i) {
        const int pbase = i * 4096 + t * 4;
        const float4* q4 = reinterpret_cast<const float4*>(base + (size_t)pbase * 3);
        float4 A = q4[0], Bv = q4[1], Cv = q4[2];
        float px[4] = { A.x, A.w, Bv.z, Cv.y };
        float py[4] = { A.y, Bv.x, Bv.w, Cv.z };
        float pz[4] = { A.z, Bv.y, Cv.x, Cv.w };
#pragma unroll
        for (int q = 0; q < 4; ++q) {
            float dx = __fsub_rn(px[q], cx);
            float dy = __fsub_rn(py[q], cy);
            float dz = __fsub_rn(pz[q], cz);
            float sq = __fadd_rn(__fadd_rn(__fmul_rn(dx, dx), __fmul_rn(dy, dy)),
                                 __fmul_rn(dz, dz));
            // branchless sorted insert, all ops independent (med3 trick)
#pragma unroll
            for (int jj = 10; jj >= 1; --jj)
                lst[jj] = __builtin_amdgcn_fmed3f(lst[jj - 1], lst[jj], sq);
            lst[0] = fminf(lst[0], sq);
        }
    }

    // ---- wave-level top-11: 11 rounds of (wave-min of heads, pop one copy) --
    __shared__ float s_top[16][11];
    for (int r = 0; r < 11; ++r) {
        float v = lst[0];
#pragma unroll
        for (int off = 32; off >= 1; off >>= 1) v = fminf(v, __shfl_xor(v, off));
        unsigned long long m = __ballot(lst[0] == v);
        if (lane == (int)__ffsll(m) - 1) {     // pop exactly one copy
#pragma unroll
            for (int jj = 0; jj < 10; ++jj) lst[jj] = lst[jj + 1];
            lst[10] = FLT_MAX;
        }
        if (lane == 0) s_top[w][r] = v;
    }
    __syncthreads();

    // ---- final merge: wave 0 merges 16 lists x 11 = 176 values -------------
    if (w == 0) {
        const float* flat = &s_top[0][0];
        float a0 = flat[lane];
        float a1 = flat[lane + 64];
        float a2 = (lane + 128 < 176) ? flat[lane + 128] : FLT_MAX;

        const float HH = (float)(0.01 * 0.01);   // JAX weak-typed scalar H*H
        float acc = 0.0f;
#pragma unroll
        for (int r = 0; r < 11; ++r) {
            float mymin = fminf(a0, fminf(a1, a2));
            float v = mymin;
#pragma unroll
            for (int off = 32; off >= 1; off >>= 1) v = fminf(v, __shfl_xor(v, off));
            unsigned long long m = __ballot(mymin == v);
            if (lane == (int)__ffsll(m) - 1) {
                if (a0 == v)      a0 = FLT_MAX;
                else if (a1 == v) a1 = FLT_MAX;
                else              a2 = FLT_MAX;
            }
            if (lane == 0 && r >= 1) {           // r==0 is self (dist 0)
                float sq = v;
                float d  = (sq == 0.0f) ? 0.0f : __fsqrt_rn(sq);
                float q2 = __fmul_rn(d, d);
                float wt = expf(__fdiv_rn(-q2, HH));
                acc = __fadd_rn(acc, -__fmul_rn(d, wt));
            }
        }
        if (lane == 0) atomicAdd(out, acc * 0.0625f);   // mean over B=16
    }
}

// ---------------- Host: JAX threefry2x32 (partitionable mode) ---------------
static inline uint32_t rotl32(uint32_t x, uint32_t d) { return (x << d) | (x >> (32 - d)); }

static void tf2x32(uint32_t k0, uint32_t k1, uint32_t x0, uint32_t x1,
                   uint32_t& y0, uint32_t& y1) {
    const uint32_t ks[3] = { k0, k1, k0 ^ k1 ^ 0x1BD11BDAu };
    const uint32_t rotA[4] = { 13, 15, 26, 6 };
    const uint32_t rotB[4] = { 17, 29, 16, 24 };
    uint32_t v0 = x0 + ks[0], v1 = x1 + ks[1];
    for (int i = 0; i < 5; ++i) {
        const uint32_t* rot = (i % 2 == 0) ? rotA : rotB;
        for (int j = 0; j < 4; ++j) {
            v0 += v1;
            v1 = rotl32(v1, rot[j]);
            v1 ^= v0;
        }
        v0 += ks[(i + 1) % 3];
        v1 += ks[(i + 2) % 3] + (uint32_t)(i + 1);
    }
    y0 = v0; y1 = v1;
}

extern "C" void kernel_launch(void* const* d_in, const int* in_sizes, int n_in,
                              void* d_out, int out_size, void* d_ws, size_t ws_size,
                              hipStream_t stream) {
    const float* pcs = (const float*)d_in[0];
    float* out = (float*)d_out;

    // ws: [0,1280) seeds (int); [2048, 2048+16*20*16*8=43008) fps keys (u64)
    int* seeds               = (int*)d_ws;
    unsigned long long* fkey = (unsigned long long*)((char*)d_ws + 2048);

    // jax.random.key(1) -> threefry key (0,1), partitionable mode:
    //   split foldlike: k2 = threefry((0,1),(0,1)) both words
    //   random_bits: counters (0,i), out = y0 ^ y1; randint span 2^16 -> mask
    uint32_t k2_0, k2_1;
    tf2x32(0u, 1u, 0u, 1u, k2_0, k2_1);
    InitIdx init;
    for (int i = 0; i < NB; ++i) {
        uint32_t y0, y1;
        tf2x32(k2_0, k2_1, 0u, (uint32_t)i, y0, y1);
        init.idx[i] = (int)((y0 ^ y1) & 0xFFFFu);
    }

    hipMemsetAsync(d_ws, 0, 43008, stream);   // seeds + fps keys
    hipMemsetAsync(d_out, 0, sizeof(float), stream);

    hipLaunchKernelGGL(fps_kernel, dim3(NB * FPB), dim3(1024), 0, stream,
                       pcs, seeds, fkey, init);
    hipLaunchKernelGGL(knn_kernel, dim3(NB * NS), dim3(1024), 0, stream,
                       pcs, seeds, out);
}

// Round 13
// 81.829 us; speedup vs baseline: 1.6651x; 1.0064x over previous
//
#include <hip/hip_runtime.h>
#include <cstdint>
#include <cfloat>
#include <cmath>

#define NPTS 65536
#define NB 16
#define NS 20
#define KK 10
#define FPB 8       // FPS blocks per batch (publishers)
#define PPT 8       // points per thread in fps (8 blk * 1024 thr * 8 = 65536)
#define NSm1 (NS - 1)

struct InitIdx { int idx[NB]; };

static __device__ __forceinline__ unsigned long long
agent_ld(const unsigned long long* p) {
    return __hip_atomic_load(p, __ATOMIC_RELAXED, __HIP_MEMORY_SCOPE_AGENT);
}

// ---------------- Kernel 1: distributed FPS (R12 structure, FPB=8) ----------
// 128 blocks (8/batch) x 1024 threads; 8 CONTIGUOUS points/thread loaded once
// as 6x float4, coords + running-min in registers. Per step: dist + min +
// wave argmax (strict >, tie -> smaller idx = JAX first-occurrence), B1,
// wave0: 16-lane block reduce -> lane0 publishes packed u64 key
// (fbits(val)<<32 | ~idx, monotone, nonzero) via relaxed agent store; 3-deep
// pipelined poll of the batch's 8 keys; B2. Fewer publishers (8 vs 16)
// shrinks the straggler tail of store-visibility latencies.
__global__ __launch_bounds__(1024) void fps_kernel(const float* __restrict__ pcs,
                                                   int* __restrict__ seeds,
                                                   unsigned long long* __restrict__ fkey,
                                                   InitIdx init) {
    const int u   = blockIdx.x;         // 0..127
    const int xcd = u & 7;              // XCD heuristic (perf-only)
    const int k   = u >> 3;             // 0..15
    const int b   = 2 * xcd + (k >> 3); // batch
    const int j   = k & 7;              // block-in-batch 0..7
    const int t   = threadIdx.x;
    const int lane = t & 63;
    const int w    = t >> 6;
    const float* __restrict__ base = pcs + (size_t)b * NPTS * 3;
    const int pbase = j * 8192 + t * 8; // 8 contiguous points per thread

    float x[PPT], y[PPT], z[PPT], dm[PPT];
    {
        const float4* q4 = reinterpret_cast<const float4*>(base + (size_t)pbase * 3);
#pragma unroll
        for (int g = 0; g < 2; ++g) {
            float4 A = q4[g * 3 + 0], Bv = q4[g * 3 + 1], Cv = q4[g * 3 + 2];
            x[g*4+0] = A.x;  y[g*4+0] = A.y;  z[g*4+0] = A.z;
            x[g*4+1] = A.w;  y[g*4+1] = Bv.x; z[g*4+1] = Bv.y;
            x[g*4+2] = Bv.z; y[g*4+2] = Bv.w; z[g*4+2] = Cv.x;
            x[g*4+3] = Cv.y; y[g*4+3] = Cv.z; z[g*4+3] = Cv.w;
        }
#pragma unroll
        for (int q = 0; q < PPT; ++q) dm[q] = 1e10f;
    }

    __shared__ float s_val[16];
    __shared__ int   s_idx[16];
    __shared__ int   s_far;

    int far = init.idx[b];

    for (int s = 0; s < NS; ++s) {
        if (j == 0 && t == 0) seeds[b * NS + s] = far;   // seed s BEFORE update
        if (s == NSm1) break;                            // last update unused

        const float* c = base + (size_t)far * 3;         // uniform, cached
        const float cx = c[0], cy = c[1], cz = c[2];

        float bestv = -1.0f;
        int   besti = 0;
#pragma unroll
        for (int q = 0; q < PPT; ++q) {
            // match XLA: rounded sub/mul, sequential adds, NO fma contraction
            float dx = __fsub_rn(x[q], cx);
            float dy = __fsub_rn(y[q], cy);
            float dz = __fsub_rn(z[q], cz);
            float d  = __fadd_rn(__fadd_rn(__fmul_rn(dx, dx), __fmul_rn(dy, dy)),
                                 __fmul_rn(dz, dz));
            dm[q] = fminf(dm[q], d);
            // q ascending = index ascending; strict > keeps first occurrence
            if (dm[q] > bestv) { bestv = dm[q]; besti = pbase + q; }
        }
#pragma unroll
        for (int off = 32; off >= 1; off >>= 1) {
            float ov = __shfl_down(bestv, off);
            int   oi = __shfl_down(besti, off);
            if (ov > bestv || (ov == bestv && oi < besti)) { bestv = ov; besti = oi; }
        }
        if (lane == 0) { s_val[w] = bestv; s_idx[w] = besti; }
        __syncthreads();                                 // B1

        if (w == 0) {
            // parallel 16-lane block reduce -> packed key -> publish
            unsigned long long kv = 0ULL;
            if (lane < 16) {
                kv = ((unsigned long long)__float_as_uint(s_val[lane]) << 32) |
                     (unsigned long long)(0xFFFFFFFFu - (unsigned int)s_idx[lane]);
            }
#pragma unroll
            for (int off = 8; off >= 1; off >>= 1) {
                unsigned int lo = (unsigned int)kv, hi = (unsigned int)(kv >> 32);
                unsigned int olo = (unsigned int)__shfl_xor((int)lo, off);
                unsigned int ohi = (unsigned int)__shfl_xor((int)hi, off);
                unsigned long long o = ((unsigned long long)ohi << 32) | olo;
                if (o > kv) kv = o;
            }
            unsigned long long* fp = fkey + (size_t)(b * NS + s) * FPB;
            if (lane == 0)
                __hip_atomic_store(&fp[j], kv, __ATOMIC_RELAXED,
                                   __HIP_MEMORY_SCOPE_AGENT);

            // 3-deep pipelined poll of the 8 slots (lane l watches slot l&7)
            const unsigned long long* sl = fp + (lane & 7);
            unsigned long long p0 = agent_ld(sl);
            unsigned long long p1 = agent_ld(sl);
            unsigned long long p2 = agent_ld(sl);
            unsigned long long v;
            for (;;) {
                if (!__any(p0 == 0ULL)) { v = p0; break; }
                p0 = agent_ld(sl);
                if (!__any(p1 == 0ULL)) { v = p1; break; }
                p1 = agent_ld(sl);
                if (!__any(p2 == 0ULL)) { v = p2; break; }
                p2 = agent_ld(sl);
            }
#pragma unroll
            for (int off = 32; off >= 1; off >>= 1) {
                unsigned int lo = (unsigned int)v, hi = (unsigned int)(v >> 32);
                unsigned int olo = (unsigned int)__shfl_xor((int)lo, off);
                unsigned int ohi = (unsigned int)__shfl_xor((int)hi, off);
                unsigned long long o = ((unsigned long long)ohi << 32) | olo;
                if (o > v) v = o;
            }
            if (lane == 0)
                s_far = (int)(0xFFFFFFFFu - (unsigned int)(v & 0xFFFFFFFFull));
        }
        __syncthreads();                                 // B2
        far = s_far;
    }
}

// ---------------- Kernel 2: knn scan (even grid, 4 chunks per seed) ---------
// 1280 blocks x 256 thr = exactly 5 blocks/CU (no distribution tail).
// Each block scans 16384 contiguous points of one (batch,seed) pair with the
// R12-verbatim med3 branchless insert (64 pts/thread); each wave's 11-pop
// writes its 11 ascending values straight to part[pair][chunk][wave][11].
__global__ __launch_bounds__(256) void knn_scan(const float* __restrict__ pcs,
                                                const int* __restrict__ seeds,
                                                float* __restrict__ part) {
    const int u   = blockIdx.x;        // 0..1279
    const int xcd = u & 7;
    const int k   = u >> 3;            // 0..159
    const int b   = 2 * xcd + (k / 80);
    const int rem = k % 80;
    const int s   = rem >> 2;          // 0..19
    const int c   = rem & 3;           // chunk 0..3
    const int t = threadIdx.x;         // 0..255
    const int lane = t & 63;
    const int w = t >> 6;              // wave 0..3
    const float* __restrict__ base = pcs + (size_t)b * NPTS * 3;
    const int sidx = seeds[b * NS + s];
    const float cx = base[(size_t)sidx * 3 + 0];
    const float cy = base[(size_t)sidx * 3 + 1];
    const float cz = base[(size_t)sidx * 3 + 2];

    float lst[11];
#pragma unroll
    for (int jj = 0; jj < 11; ++jj) lst[jj] = FLT_MAX;

    for (int i = 0; i < 16; ++i) {
        const int pbase = c * 16384 + i * 1024 + t * 4;
        const float4* q4 = reinterpret_cast<const float4*>(base + (size_t)pbase * 3);
        float4 A = q4[0], Bv = q4[1], Cv = q4[2];
        float px[4] = { A.x, A.w, Bv.z, Cv.y };
        float py[4] = { A.y, Bv.x, Bv.w, Cv.z };
        float pz[4] = { A.z, Bv.y, Cv.x, Cv.w };
#pragma unroll
        for (int q = 0; q < 4; ++q) {
            float dx = __fsub_rn(px[q], cx);
            float dy = __fsub_rn(py[q], cy);
            float dz = __fsub_rn(pz[q], cz);
            float sq = __fadd_rn(__fadd_rn(__fmul_rn(dx, dx), __fmul_rn(dy, dy)),
                                 __fmul_rn(dz, dz));
            // branchless sorted insert, all ops independent (med3 trick)
#pragma unroll
            for (int jj = 10; jj >= 1; --jj)
                lst[jj] = __builtin_amdgcn_fmed3f(lst[jj - 1], lst[jj], sq);
            lst[0] = fminf(lst[0], sq);
        }
    }

    // wave-level top-11: 11 rounds of (wave-min of heads, pop one copy);
    // round r's min is the wave's r-th smallest -> store to part directly.
    float* pr = part + ((size_t)((b * NS + s) * 4 + c) * 4 + w) * 11;
    for (int r = 0; r < 11; ++r) {
        float v = lst[0];
#pragma unroll
        for (int off = 32; off >= 1; off >>= 1) v = fminf(v, __shfl_xor(v, off));
        unsigned long long m = __ballot(lst[0] == v);
        if (lane == (int)__ffsll(m) - 1) {     // pop exactly one copy
#pragma unroll
            for (int jj = 0; jj < 10; ++jj) lst[jj] = lst[jj + 1];
            lst[10] = FLT_MAX;
        }
        if (lane == 0) pr[r] = v;
    }
}

// ---------------- Kernel 3: merge 176 -> top-11 + repulsion epilogue --------
// 320 blocks x 1 wave; R12-verbatim final-merge pattern reading global part.
__global__ __launch_bounds__(64) void knn_merge(const float* __restrict__ part,
                                                float* __restrict__ out) {
    const int pair = blockIdx.x;       // 0..319
    const int lane = threadIdx.x;      // 0..63
    const float* flat = part + (size_t)pair * 176;
    float a0 = flat[lane];
    float a1 = flat[lane + 64];
    float a2 = (lane + 128 < 176) ? flat[lane + 128] : FLT_MAX;

    const float HH = (float)(0.01 * 0.01);   // JAX weak-typed scalar H*H
    float acc = 0.0f;
#pragma unroll
    for (int r = 0; r < 11; ++r) {
        float mymin = fminf(a0, fminf(a1, a2));
        float v = mymin;
#pragma unroll
        for (int off = 32; off >= 1; off >>= 1) v = fminf(v, __shfl_xor(v, off));
        unsigned long long m = __ballot(mymin == v);
        if (lane == (int)__ffsll(m) - 1) {
            if (a0 == v)      a0 = FLT_MAX;
            else if (a1 == v) a1 = FLT_MAX;
            else              a2 = FLT_MAX;
        }
        if (lane == 0 && r >= 1) {           // r==0 is self (dist 0)
            float sq = v;
            float d  = (sq == 0.0f) ? 0.0f : __fsqrt_rn(sq);
            float q2 = __fmul_rn(d, d);
            float wt = expf(__fdiv_rn(-q2, HH));
            acc = __fadd_rn(acc, -__fmul_rn(d, wt));
        }
    }
    if (lane == 0) atomicAdd(out, acc * 0.0625f);   // mean over B=16
}

// ---------------- Host: JAX threefry2x32 (partitionable mode) ---------------
static inline uint32_t rotl32(uint32_t x, uint32_t d) { return (x << d) | (x >> (32 - d)); }

static void tf2x32(uint32_t k0, uint32_t k1, uint32_t x0, uint32_t x1,
                   uint32_t& y0, uint32_t& y1) {
    const uint32_t ks[3] = { k0, k1, k0 ^ k1 ^ 0x1BD11BDAu };
    const uint32_t rotA[4] = { 13, 15, 26, 6 };
    const uint32_t rotB[4] = { 17, 29, 16, 24 };
    uint32_t v0 = x0 + ks[0], v1 = x1 + ks[1];
    for (int i = 0; i < 5; ++i) {
        const uint32_t* rot = (i % 2 == 0) ? rotA : rotB;
        for (int j = 0; j < 4; ++j) {
            v0 += v1;
            v1 = rotl32(v1, rot[j]);
            v1 ^= v0;
        }
        v0 += ks[(i + 1) % 3];
        v1 += ks[(i + 2) % 3] + (uint32_t)(i + 1);
    }
    y0 = v0; y1 = v1;
}

extern "C" void kernel_launch(void* const* d_in, const int* in_sizes, int n_in,
                              void* d_out, int out_size, void* d_ws, size_t ws_size,
                              hipStream_t stream) {
    const float* pcs = (const float*)d_in[0];
    float* out = (float*)d_out;

    // ws: [0,1280) seeds (int); [2048, 22528) fps keys u64[16*20*8];
    //     [24576, 249856) part f32[320*176]
    int* seeds               = (int*)d_ws;
    unsigned long long* fkey = (unsigned long long*)((char*)d_ws + 2048);
    float* part              = (float*)((char*)d_ws + 24576);

    // jax.random.key(1) -> threefry key (0,1), partitionable mode:
    //   split foldlike: k2 = threefry((0,1),(0,1)) both words
    //   random_bits: counters (0,i), out = y0 ^ y1; randint span 2^16 -> mask
    uint32_t k2_0, k2_1;
    tf2x32(0u, 1u, 0u, 1u, k2_0, k2_1);
    InitIdx init;
    for (int i = 0; i < NB; ++i) {
        uint32_t y0, y1;
        tf2x32(k2_0, k2_1, 0u, (uint32_t)i, y0, y1);
        init.idx[i] = (int)((y0 ^ y1) & 0xFFFFu);
    }

    hipMemsetAsync(d_ws, 0, 22528, stream);   // seeds + fps key slots
    hipMemsetAsync(d_out, 0, sizeof(float), stream);

    hipLaunchKernelGGL(fps_kernel, dim3(NB * FPB), dim3(1024), 0, stream,
                       pcs, seeds, fkey, init);
    hipLaunchKernelGGL(knn_scan, dim3(1280), dim3(256), 0, stream,
                       pcs, seeds, part);
    hipLaunchKernelGGL(knn_merge, dim3(320), dim3(64), 0, stream,
                       part, out);
}